// Round 5
// baseline (2035.864 us; speedup 1.0000x reference)
//
#include <hip/hip_runtime.h>
#include <math.h>

#define DFEAT 128
#define EPS_C 0.01f

using f4 = __attribute__((ext_vector_type(4))) float;
using i2 = __attribute__((ext_vector_type(2))) int;

// ---------------- edge preprocessing ----------------

// rank[e] = position of edge e within its row (via count histogram atomic).
__global__ __launch_bounds__(256) void edge_prep_kernel(
    const int* __restrict__ rows, int* __restrict__ rank,
    int* __restrict__ count, int E)
{
    int e = blockIdx.x * 256 + threadIdx.x;
    if (e >= E) return;
    rank[e] = atomicAdd(&count[rows[e]], 1);
}

// exclusive scan of count -> row_start.  1024 elements per block.
__global__ __launch_bounds__(256) void scan_a_kernel(
    const int* __restrict__ cnt, int* __restrict__ rs, int* __restrict__ bsum, int N)
{
    __shared__ int lds[256];
    int tid = threadIdx.x;
    int idx = blockIdx.x * 1024 + tid * 4;
    int v0 = 0, v1 = 0, v2 = 0, v3 = 0;
    if (idx + 3 < N) {
        int4 cv = *(const int4*)(cnt + idx);
        v0 = cv.x; v1 = cv.y; v2 = cv.z; v3 = cv.w;
    } else {
        if (idx     < N) v0 = cnt[idx];
        if (idx + 1 < N) v1 = cnt[idx + 1];
        if (idx + 2 < N) v2 = cnt[idx + 2];
        if (idx + 3 < N) v3 = cnt[idx + 3];
    }
    int tsum = v0 + v1 + v2 + v3;
    lds[tid] = tsum;
    __syncthreads();
    for (int off = 1; off < 256; off <<= 1) {
        int x = lds[tid];
        int y = (tid >= off) ? lds[tid - off] : 0;
        __syncthreads();
        lds[tid] = x + y;
        __syncthreads();
    }
    int tprefix = lds[tid] - tsum;   // exclusive prefix of this thread's chunk
    if (tid == 255) bsum[blockIdx.x] = lds[255];
    int p = tprefix;
    if (idx     < N) rs[idx]     = p;  p += v0;
    if (idx + 1 < N) rs[idx + 1] = p;  p += v1;
    if (idx + 2 < N) rs[idx + 2] = p;  p += v2;
    if (idx + 3 < N) rs[idx + 3] = p;
}

__global__ void scan_b_kernel(int* __restrict__ bsum, int nb)
{
    if (threadIdx.x == 0 && blockIdx.x == 0) {
        int run = 0;
        for (int i = 0; i < nb; i++) { int t = bsum[i]; bsum[i] = run; run += t; }
    }
}

__global__ __launch_bounds__(256) void scan_c_kernel(
    int* __restrict__ rs, const int* __restrict__ bsum, int N)
{
    int i = blockIdx.x * 256 + threadIdx.x;
    if (i >= N) return;
    rs[i] += bsum[i >> 10];
}

// scatter (no atomics): pos = rs[row] + rank. Recomputes conductance here.
__global__ __launch_bounds__(256) void scatter_kernel(
    const int* __restrict__ rows, const int* __restrict__ cols,
    const float* __restrict__ wval, const float* __restrict__ kappa,
    const float* __restrict__ alpha_p, const float* __restrict__ center_p,
    const int* __restrict__ rank, const int* __restrict__ rs,
    i2* __restrict__ edges, int E)
{
    int e = blockIdx.x * 256 + threadIdx.x;
    if (e >= E) return;
    float a = alpha_p[0];
    float c = center_p[0];
    float sp = (a > 20.f) ? a : log1pf(expf(a));       // softplus(alpha)
    float z = sp * (kappa[e] - c);
    float sig = 1.f / (1.f + expf(-z));
    float wp = wval[e] * (EPS_C + (1.f - EPS_C) * sig);
    int pos = rs[rows[e]] + rank[e];
    i2 ed; ed.x = cols[e]; ed.y = __float_as_int(wp);
    edges[pos] = ed;
}

// per-row degree from CSR (contiguous, no atomics) -> dinv
__global__ __launch_bounds__(256) void row_deg_kernel(
    const i2* __restrict__ edges, const int* __restrict__ rs,
    const int* __restrict__ cnt, float* __restrict__ dinv, int N)
{
    int r = blockIdx.x * 256 + threadIdx.x;
    if (r >= N) return;
    int s = rs[r], e = s + cnt[r];
    float d = 0.f;
    for (int i = s; i < e; i++) d += __int_as_float(edges[i].y);
    dinv[r] = 1.f / (sqrtf(d) + 1e-8f);
}

// ---------------- Chebyshev SpMM (fused recurrence + accumulate) ----------------
// ONE ROW PER HALF-WAVE: 32 lanes x float4 = 512B = full feature row.
// 8-edge unroll -> 16 independent gathers in flight per wave (MLP 2x vs R3).
// No cross-lane reduction needed; each half does its own epilogue.
// FIRST=1: scales weights by dinv on the fly and writes them back; Tnew=-sum;
//          acc = c0*X + ck*Tnew.
// FIRST=0: Tnew = -2*sum - Tprev; acc += ck*Tnew.  (Tnew may alias Tprev.)
//          writeT==0 skips the Tnew store (final step).
template<int FIRST>
__global__ __launch_bounds__(256) void cheb_spmm_kernel(
    i2* __restrict__ edges, const int* __restrict__ rs,
    const int* __restrict__ cnt, const float* __restrict__ dinv,
    const float* __restrict__ Tcur, const float* __restrict__ Tprev,
    float* __restrict__ Tnew, float* __restrict__ acc,
    const float* __restrict__ X, float c0, float ck, int writeT, int N)
{
    int row = (blockIdx.x * blockDim.x + threadIdx.x) >> 5;   // half-wave id
    if (row >= N) return;
    int fl = threadIdx.x & 31;     // feature lane: floats fl*4 .. fl*4+3
    int s = rs[row];
    int e = s + cnt[row];

    f4 aa;
    if (FIRST) {
        float dr = dinv[row];
        f4 a0 = (f4)0.f;
        for (int i = s; i < e; i++) {
            i2 ed = edges[i];
            float wn = dr * __int_as_float(ed.y) * dinv[ed.x];
            f4 v = *(const f4*)(Tcur + (size_t)ed.x * DFEAT + fl * 4);
            a0 += wn * v;
            if (fl == 0) ((int*)edges)[2 * (size_t)i + 1] = __float_as_int(wn);
        }
        aa = a0;
    } else {
        f4 a0 = (f4)0.f, a1 = (f4)0.f, a2 = (f4)0.f, a3 = (f4)0.f;
        int i = s;
        for (; i + 7 < e; i += 8) {
            i2 e0 = edges[i];
            i2 e1 = edges[i + 1];
            i2 e2 = edges[i + 2];
            i2 e3 = edges[i + 3];
            i2 e4 = edges[i + 4];
            i2 e5 = edges[i + 5];
            i2 e6 = edges[i + 6];
            i2 e7 = edges[i + 7];
            f4 v0 = *(const f4*)(Tcur + (size_t)e0.x * DFEAT + fl * 4);
            f4 v1 = *(const f4*)(Tcur + (size_t)e1.x * DFEAT + fl * 4);
            f4 v2 = *(const f4*)(Tcur + (size_t)e2.x * DFEAT + fl * 4);
            f4 v3 = *(const f4*)(Tcur + (size_t)e3.x * DFEAT + fl * 4);
            f4 v4 = *(const f4*)(Tcur + (size_t)e4.x * DFEAT + fl * 4);
            f4 v5 = *(const f4*)(Tcur + (size_t)e5.x * DFEAT + fl * 4);
            f4 v6 = *(const f4*)(Tcur + (size_t)e6.x * DFEAT + fl * 4);
            f4 v7 = *(const f4*)(Tcur + (size_t)e7.x * DFEAT + fl * 4);
            a0 += __int_as_float(e0.y) * v0;
            a1 += __int_as_float(e1.y) * v1;
            a2 += __int_as_float(e2.y) * v2;
            a3 += __int_as_float(e3.y) * v3;
            a0 += __int_as_float(e4.y) * v4;
            a1 += __int_as_float(e5.y) * v5;
            a2 += __int_as_float(e6.y) * v6;
            a3 += __int_as_float(e7.y) * v7;
        }
        for (; i + 1 < e; i += 2) {
            i2 e0 = edges[i];
            i2 e1 = edges[i + 1];
            f4 v0 = *(const f4*)(Tcur + (size_t)e0.x * DFEAT + fl * 4);
            f4 v1 = *(const f4*)(Tcur + (size_t)e1.x * DFEAT + fl * 4);
            a0 += __int_as_float(e0.y) * v0;
            a1 += __int_as_float(e1.y) * v1;
        }
        if (i < e) {
            i2 e0 = edges[i];
            f4 v0 = *(const f4*)(Tcur + (size_t)e0.x * DFEAT + fl * 4);
            a0 += __int_as_float(e0.y) * v0;
        }
        aa = (a0 + a1) + (a2 + a3);
    }

    size_t off = (size_t)row * DFEAT + fl * 4;
    if (FIRST) {
        f4 tn = -aa;
        *(f4*)(Tnew + off) = tn;
        f4 xv = *(const f4*)(X + off);
        *(f4*)(acc + off) = c0 * xv + ck * tn;
    } else {
        f4 tp = *(const f4*)(Tprev + off);
        f4 tn = -2.f * aa - tp;
        if (writeT) *(f4*)(Tnew + off) = tn;
        f4 av = *(const f4*)(acc + off);
        *(f4*)(acc + off) = av + ck * tn;
    }
}

// ---------------- host ----------------

static void cheb_coeffs_host(float* cf)
{
    const int m = 30;
    const double t_scale = 5.0, lambda_max = 2.0;
    double xv[30], fv[30], th[30];
    for (int j = 0; j < m; j++) {
        th[j] = M_PI * (j + 0.5) / m;
        xv[j] = cos(th[j]);
        double lam = lambda_max / 2.0 * (xv[j] + 1.0);
        fv[j] = exp(-t_scale * lam);
    }
    for (int k = 0; k < m; k++) {
        double s = 0.0;
        for (int j = 0; j < m; j++) s += fv[j] * cos((double)k * th[j]);
        double v = 2.0 / m * s;
        if (k == 0) v *= 0.5;
        cf[k] = (float)v;
    }
}

extern "C" void kernel_launch(void* const* d_in, const int* in_sizes, int n_in,
                              void* d_out, int out_size, void* d_ws, size_t ws_size,
                              hipStream_t stream)
{
    const int*   Widx   = (const int*)d_in[0];
    const float* Wval   = (const float*)d_in[1];
    const float* kappa  = (const float*)d_in[2];
    const float* X      = (const float*)d_in[3];
    const float* alpha  = (const float*)d_in[4];
    const float* center = (const float*)d_in[5];

    int E = in_sizes[1];
    int N = in_sizes[3] / DFEAT;
    const int* rows = Widx;
    const int* cols = Widx + E;
    float* out = (float*)d_out;

    // workspace layout (256B aligned chunks)  — total ~123 MB
    char* p = (char*)d_ws;
    auto alloc = [&](size_t bytes) -> void* {
        void* r = (void*)p;
        p += (bytes + 255) & ~((size_t)255);
        return r;
    };
    float* bufA  = (float*)alloc((size_t)N * DFEAT * 4);
    float* bufB  = (float*)alloc((size_t)N * DFEAT * 4);
    int*   rank  = (int*)alloc((size_t)E * 4);
    int*   count = (int*)alloc((size_t)N * 4);
    int*   rs    = (int*)alloc((size_t)N * 4);
    float* dinv  = (float*)alloc((size_t)N * 4);
    int*   bsum  = (int*)alloc(4096);
    i2*    edges = (i2*)alloc((size_t)E * 8);

    hipMemsetAsync(count, 0, (size_t)N * 4, stream);

    float cf[30];
    cheb_coeffs_host(cf);

    // Truncate the series where coefficients are numerically negligible.
    // |c_k| = 2 e^-5 I_k(5): c_12~2.9e-6, c_14~1.1e-7, c_15~2e-8. Terms past
    // |c_k|<1e-7 contribute <<1e-5 to the output (threshold 3.3e-3).
    int K = 29;
    while (K > 10 && fabsf(cf[K]) < 1e-7f) K--;

    int ge = (E + 255) / 256;
    int gn = (N + 255) / 256;

    edge_prep_kernel<<<ge, 256, 0, stream>>>(rows, rank, count, E);

    int nb = (N + 1023) / 1024;
    scan_a_kernel<<<nb, 256, 0, stream>>>(count, rs, bsum, N);
    scan_b_kernel<<<1, 64, 0, stream>>>(bsum, nb);
    scan_c_kernel<<<gn, 256, 0, stream>>>(rs, bsum, N);

    scatter_kernel<<<ge, 256, 0, stream>>>(rows, cols, Wval, kappa, alpha, center,
                                           rank, rs, edges, E);
    row_deg_kernel<<<gn, 256, 0, stream>>>(edges, rs, count, dinv, N);

    int spmm_blocks = (int)(((size_t)N * 32 + 255) / 256);   // half-wave per row

    // T1 = L X ; acc = c0*X + c1*T1   (scales+writes back edge weights)
    cheb_spmm_kernel<1><<<spmm_blocks, 256, 0, stream>>>(
        edges, rs, count, dinv, X, X, bufA, out, X, cf[0], cf[1], 1, N);

    const float* Tprev = X;
    const float* Tcur  = bufA;
    float*       Tnew  = bufB;
    for (int k = 2; k <= K; k++) {
        cheb_spmm_kernel<0><<<spmm_blocks, 256, 0, stream>>>(
            edges, rs, count, dinv, Tcur, Tprev, Tnew, out, X, 0.f, cf[k],
            (k < K) ? 1 : 0, N);
        const float* newPrev = Tcur;
        const float* newCur  = Tnew;
        Tnew  = (float*)Tcur;   // overwrite the retiring T_{k-1} buffer in place
        Tprev = newPrev;
        Tcur  = newCur;
    }
}

// Round 6
// 1223.262 us; speedup vs baseline: 1.6643x; 1.6643x over previous
//
#include <hip/hip_runtime.h>
#include <math.h>

#define DFEAT 128
#define EPS_C 0.01f

using f4 = __attribute__((ext_vector_type(4))) float;
using h4 = __attribute__((ext_vector_type(4))) _Float16;
using i2 = __attribute__((ext_vector_type(2))) int;

// ---------------- edge preprocessing ----------------

// rank[e] = position of edge e within its row (via count histogram atomic).
__global__ __launch_bounds__(256) void edge_prep_kernel(
    const int* __restrict__ rows, int* __restrict__ rank,
    int* __restrict__ count, int E)
{
    int e = blockIdx.x * 256 + threadIdx.x;
    if (e >= E) return;
    rank[e] = atomicAdd(&count[rows[e]], 1);
}

// exclusive scan of count -> row_start.  1024 elements per block.
__global__ __launch_bounds__(256) void scan_a_kernel(
    const int* __restrict__ cnt, int* __restrict__ rs, int* __restrict__ bsum, int N)
{
    __shared__ int lds[256];
    int tid = threadIdx.x;
    int idx = blockIdx.x * 1024 + tid * 4;
    int v0 = 0, v1 = 0, v2 = 0, v3 = 0;
    if (idx + 3 < N) {
        int4 cv = *(const int4*)(cnt + idx);
        v0 = cv.x; v1 = cv.y; v2 = cv.z; v3 = cv.w;
    } else {
        if (idx     < N) v0 = cnt[idx];
        if (idx + 1 < N) v1 = cnt[idx + 1];
        if (idx + 2 < N) v2 = cnt[idx + 2];
        if (idx + 3 < N) v3 = cnt[idx + 3];
    }
    int tsum = v0 + v1 + v2 + v3;
    lds[tid] = tsum;
    __syncthreads();
    for (int off = 1; off < 256; off <<= 1) {
        int x = lds[tid];
        int y = (tid >= off) ? lds[tid - off] : 0;
        __syncthreads();
        lds[tid] = x + y;
        __syncthreads();
    }
    int tprefix = lds[tid] - tsum;   // exclusive prefix of this thread's chunk
    if (tid == 255) bsum[blockIdx.x] = lds[255];
    int p = tprefix;
    if (idx     < N) rs[idx]     = p;  p += v0;
    if (idx + 1 < N) rs[idx + 1] = p;  p += v1;
    if (idx + 2 < N) rs[idx + 2] = p;  p += v2;
    if (idx + 3 < N) rs[idx + 3] = p;
}

__global__ void scan_b_kernel(int* __restrict__ bsum, int nb)
{
    if (threadIdx.x == 0 && blockIdx.x == 0) {
        int run = 0;
        for (int i = 0; i < nb; i++) { int t = bsum[i]; bsum[i] = run; run += t; }
    }
}

__global__ __launch_bounds__(256) void scan_c_kernel(
    int* __restrict__ rs, const int* __restrict__ bsum, int N)
{
    int i = blockIdx.x * 256 + threadIdx.x;
    if (i >= N) return;
    rs[i] += bsum[i >> 10];
}

// scatter (no atomics): pos = rs[row] + rank. Recomputes conductance here.
__global__ __launch_bounds__(256) void scatter_kernel(
    const int* __restrict__ rows, const int* __restrict__ cols,
    const float* __restrict__ wval, const float* __restrict__ kappa,
    const float* __restrict__ alpha_p, const float* __restrict__ center_p,
    const int* __restrict__ rank, const int* __restrict__ rs,
    i2* __restrict__ edges, int E)
{
    int e = blockIdx.x * 256 + threadIdx.x;
    if (e >= E) return;
    float a = alpha_p[0];
    float c = center_p[0];
    float sp = (a > 20.f) ? a : log1pf(expf(a));       // softplus(alpha)
    float z = sp * (kappa[e] - c);
    float sig = 1.f / (1.f + expf(-z));
    float wp = wval[e] * (EPS_C + (1.f - EPS_C) * sig);
    int pos = rs[rows[e]] + rank[e];
    i2 ed; ed.x = cols[e]; ed.y = __float_as_int(wp);
    edges[pos] = ed;
}

// per-row degree from CSR (contiguous, no atomics) -> dinv
__global__ __launch_bounds__(256) void row_deg_kernel(
    const i2* __restrict__ edges, const int* __restrict__ rs,
    const int* __restrict__ cnt, float* __restrict__ dinv, int N)
{
    int r = blockIdx.x * 256 + threadIdx.x;
    if (r >= N) return;
    int s = rs[r], e = s + cnt[r];
    float d = 0.f;
    for (int i = s; i < e; i++) d += __int_as_float(edges[i].y);
    dinv[r] = 1.f / (sqrtf(d) + 1e-8f);
}

// f32 -> f16 convert (4 elems/thread)
__global__ __launch_bounds__(256) void cvt_f16_kernel(
    const float* __restrict__ in, _Float16* __restrict__ out, int n4)
{
    int i = blockIdx.x * 256 + threadIdx.x;
    if (i >= n4) return;
    f4 v = *(const f4*)(in + (size_t)i * 4);
    *(h4*)(out + (size_t)i * 4) = __builtin_convertvector(v, h4);
}

// ---------------- Chebyshev SpMM (fused recurrence + accumulate) ----------------
// T-state is fp16 (256B rows), accumulation f32. One row per half-wave:
// 32 lanes x h4 (8B) = 256B row. 8-edge unroll.
// FIRST=1: scales weights by dinv on the fly and writes them back; Tnew=-sum;
//          acc = c0*X + ck*Tnew (X read from f16 copy).
// FIRST=0: Tnew = -2*sum - Tprev; acc += ck*Tnew.  (Tnew may alias Tprev.)
//          writeT==0 skips the Tnew store (final step).
template<int FIRST>
__global__ __launch_bounds__(256) void cheb_spmm_kernel(
    i2* __restrict__ edges, const int* __restrict__ rs,
    const int* __restrict__ cnt, const float* __restrict__ dinv,
    const _Float16* __restrict__ Tcur, const _Float16* __restrict__ Tprev,
    _Float16* __restrict__ Tnew, float* __restrict__ acc,
    const _Float16* __restrict__ Xh, float c0, float ck, int writeT, int N)
{
    int row = (blockIdx.x * blockDim.x + threadIdx.x) >> 5;   // half-wave id
    if (row >= N) return;
    int fl = threadIdx.x & 31;     // feature lane: features fl*4 .. fl*4+3
    int s = rs[row];
    int e = s + cnt[row];

    f4 aa;
    if (FIRST) {
        float dr = dinv[row];
        f4 a0 = (f4)0.f;
        for (int i = s; i < e; i++) {
            i2 ed = edges[i];
            float wn = dr * __int_as_float(ed.y) * dinv[ed.x];
            h4 v = *(const h4*)(Tcur + (size_t)ed.x * DFEAT + fl * 4);
            a0 += wn * __builtin_convertvector(v, f4);
            if (fl == 0) ((int*)edges)[2 * (size_t)i + 1] = __float_as_int(wn);
        }
        aa = a0;
    } else {
        f4 a0 = (f4)0.f, a1 = (f4)0.f, a2 = (f4)0.f, a3 = (f4)0.f;
        int i = s;
        for (; i + 7 < e; i += 8) {
            i2 e0 = edges[i];
            i2 e1 = edges[i + 1];
            i2 e2 = edges[i + 2];
            i2 e3 = edges[i + 3];
            i2 e4 = edges[i + 4];
            i2 e5 = edges[i + 5];
            i2 e6 = edges[i + 6];
            i2 e7 = edges[i + 7];
            h4 v0 = *(const h4*)(Tcur + (size_t)e0.x * DFEAT + fl * 4);
            h4 v1 = *(const h4*)(Tcur + (size_t)e1.x * DFEAT + fl * 4);
            h4 v2 = *(const h4*)(Tcur + (size_t)e2.x * DFEAT + fl * 4);
            h4 v3 = *(const h4*)(Tcur + (size_t)e3.x * DFEAT + fl * 4);
            h4 v4 = *(const h4*)(Tcur + (size_t)e4.x * DFEAT + fl * 4);
            h4 v5 = *(const h4*)(Tcur + (size_t)e5.x * DFEAT + fl * 4);
            h4 v6 = *(const h4*)(Tcur + (size_t)e6.x * DFEAT + fl * 4);
            h4 v7 = *(const h4*)(Tcur + (size_t)e7.x * DFEAT + fl * 4);
            a0 += __int_as_float(e0.y) * __builtin_convertvector(v0, f4);
            a1 += __int_as_float(e1.y) * __builtin_convertvector(v1, f4);
            a2 += __int_as_float(e2.y) * __builtin_convertvector(v2, f4);
            a3 += __int_as_float(e3.y) * __builtin_convertvector(v3, f4);
            a0 += __int_as_float(e4.y) * __builtin_convertvector(v4, f4);
            a1 += __int_as_float(e5.y) * __builtin_convertvector(v5, f4);
            a2 += __int_as_float(e6.y) * __builtin_convertvector(v6, f4);
            a3 += __int_as_float(e7.y) * __builtin_convertvector(v7, f4);
        }
        for (; i + 1 < e; i += 2) {
            i2 e0 = edges[i];
            i2 e1 = edges[i + 1];
            h4 v0 = *(const h4*)(Tcur + (size_t)e0.x * DFEAT + fl * 4);
            h4 v1 = *(const h4*)(Tcur + (size_t)e1.x * DFEAT + fl * 4);
            a0 += __int_as_float(e0.y) * __builtin_convertvector(v0, f4);
            a1 += __int_as_float(e1.y) * __builtin_convertvector(v1, f4);
        }
        if (i < e) {
            i2 e0 = edges[i];
            h4 v0 = *(const h4*)(Tcur + (size_t)e0.x * DFEAT + fl * 4);
            a0 += __int_as_float(e0.y) * __builtin_convertvector(v0, f4);
        }
        aa = (a0 + a1) + (a2 + a3);
    }

    size_t off = (size_t)row * DFEAT + fl * 4;
    if (FIRST) {
        f4 tn = -aa;
        *(h4*)(Tnew + off) = __builtin_convertvector(tn, h4);
        f4 xv = __builtin_convertvector(*(const h4*)(Xh + off), f4);
        *(f4*)(acc + off) = c0 * xv + ck * tn;
    } else {
        f4 tp = __builtin_convertvector(*(const h4*)(Tprev + off), f4);
        f4 tn = -2.f * aa - tp;
        if (writeT) *(h4*)(Tnew + off) = __builtin_convertvector(tn, h4);
        f4 av = *(const f4*)(acc + off);
        *(f4*)(acc + off) = av + ck * tn;
    }
}

// ---------------- host ----------------

static void cheb_coeffs_host(float* cf)
{
    const int m = 30;
    const double t_scale = 5.0, lambda_max = 2.0;
    double xv[30], fv[30], th[30];
    for (int j = 0; j < m; j++) {
        th[j] = M_PI * (j + 0.5) / m;
        xv[j] = cos(th[j]);
        double lam = lambda_max / 2.0 * (xv[j] + 1.0);
        fv[j] = exp(-t_scale * lam);
    }
    for (int k = 0; k < m; k++) {
        double s = 0.0;
        for (int j = 0; j < m; j++) s += fv[j] * cos((double)k * th[j]);
        double v = 2.0 / m * s;
        if (k == 0) v *= 0.5;
        cf[k] = (float)v;
    }
}

extern "C" void kernel_launch(void* const* d_in, const int* in_sizes, int n_in,
                              void* d_out, int out_size, void* d_ws, size_t ws_size,
                              hipStream_t stream)
{
    const int*   Widx   = (const int*)d_in[0];
    const float* Wval   = (const float*)d_in[1];
    const float* kappa  = (const float*)d_in[2];
    const float* X      = (const float*)d_in[3];
    const float* alpha  = (const float*)d_in[4];
    const float* center = (const float*)d_in[5];

    int E = in_sizes[1];
    int N = in_sizes[3] / DFEAT;
    const int* rows = Widx;
    const int* cols = Widx + E;
    float* out = (float*)d_out;

    // workspace layout (256B aligned chunks)  — total ~98 MB
    char* p = (char*)d_ws;
    auto alloc = [&](size_t bytes) -> void* {
        void* r = (void*)p;
        p += (bytes + 255) & ~((size_t)255);
        return r;
    };
    _Float16* bufA = (_Float16*)alloc((size_t)N * DFEAT * 2);
    _Float16* bufB = (_Float16*)alloc((size_t)N * DFEAT * 2);
    _Float16* Xh   = (_Float16*)alloc((size_t)N * DFEAT * 2);
    int*   rank  = (int*)alloc((size_t)E * 4);
    int*   count = (int*)alloc((size_t)N * 4);
    int*   rs    = (int*)alloc((size_t)N * 4);
    float* dinv  = (float*)alloc((size_t)N * 4);
    int*   bsum  = (int*)alloc(4096);
    i2*    edges = (i2*)alloc((size_t)E * 8);

    hipMemsetAsync(count, 0, (size_t)N * 4, stream);

    float cf[30];
    cheb_coeffs_host(cf);

    // Truncate: |c_k| = 2 e^-5 I_k(5); c_11~1.3e-5, c_12~2.7e-6, c_13~4.9e-7.
    // Dropping terms with |c_k|<1e-6 adds < ~3e-6 to the output (thr 3.3e-3).
    int K = 29;
    while (K > 8 && fabsf(cf[K]) < 1e-6f) K--;

    int ge = (E + 255) / 256;
    int gn = (N + 255) / 256;

    edge_prep_kernel<<<ge, 256, 0, stream>>>(rows, rank, count, E);

    int nb = (N + 1023) / 1024;
    scan_a_kernel<<<nb, 256, 0, stream>>>(count, rs, bsum, N);
    scan_b_kernel<<<1, 64, 0, stream>>>(bsum, nb);
    scan_c_kernel<<<gn, 256, 0, stream>>>(rs, bsum, N);

    scatter_kernel<<<ge, 256, 0, stream>>>(rows, cols, Wval, kappa, alpha, center,
                                           rank, rs, edges, E);
    row_deg_kernel<<<gn, 256, 0, stream>>>(edges, rs, count, dinv, N);

    int n4 = N * (DFEAT / 4);
    cvt_f16_kernel<<<(n4 + 255) / 256, 256, 0, stream>>>(X, Xh, n4);

    int spmm_blocks = (int)(((size_t)N * 32 + 255) / 256);   // half-wave per row

    // T1 = L X ; acc = c0*X + c1*T1   (scales+writes back edge weights)
    cheb_spmm_kernel<1><<<spmm_blocks, 256, 0, stream>>>(
        edges, rs, count, dinv, Xh, Xh, bufA, out, Xh, cf[0], cf[1], 1, N);

    const _Float16* Tprev = Xh;
    const _Float16* Tcur  = bufA;
    _Float16*       Tnew  = bufB;
    for (int k = 2; k <= K; k++) {
        cheb_spmm_kernel<0><<<spmm_blocks, 256, 0, stream>>>(
            edges, rs, count, dinv, Tcur, Tprev, Tnew, out, Xh, 0.f, cf[k],
            (k < K) ? 1 : 0, N);
        const _Float16* newPrev = Tcur;
        const _Float16* newCur  = Tnew;
        Tnew  = (_Float16*)Tcur;  // overwrite the retiring T_{k-1} buffer in place
        Tprev = newPrev;
        Tcur  = newCur;
    }
}